// Round 15
// baseline (681.401 us; speedup 1.0000x reference)
//
#include <hip/hip_runtime.h>
#include <hip/hip_bf16.h>
#include <math.h>

// MoE: T=65536 tokens, D=512, H=1024, E=8, TOP_K=2.
// R15: gate1 thread tile 16x4 -> 8x8 (64 FMA per 4 LDS reads, was per 5;
// FMA-issue density 68->73%). Transposes merged into one launch.
// Everything else identical to R14 (verified).

typedef __attribute__((ext_vector_type(8))) short bf16x8;
typedef __attribute__((ext_vector_type(4))) float f32x4;

__device__ __forceinline__ unsigned short f2bf(float f){
  unsigned u = __builtin_bit_cast(unsigned, f);
  u += 0x7FFFu + ((u >> 16) & 1u);          // RNE
  return (unsigned short)(u >> 16);
}

__device__ __forceinline__ float bf2f(unsigned short u){
  return __builtin_bit_cast(float, (unsigned)u << 16);
}

__device__ __forceinline__ float gelu_fast(float v){
  // v * sigmoid(1.59576909*(v+0.044715v^3))  (tanh-form gelu)
  float z = 1.59576909f * v * fmaf(0.044715f, v * v, 1.f);
  return v / (1.f + __expf(-z));
}

__device__ __forceinline__ void gload16(const void* g, void* l){
  __builtin_amdgcn_global_load_lds((const __attribute__((address_space(1))) unsigned int*)g,
                                   (__attribute__((address_space(3))) unsigned int*)l, 16, 0, 0);
}

// ---------------------------------------------------------------------------
// Transpose + fp32->bf16 convert, both weights in one launch:
// b < 1024: we1 [8][512][1024] -> we1T [8][1024][512]
// b >= 1024: we2 [8][1024][512] -> we2T [8][512][1024]
// ---------------------------------------------------------------------------
__global__ __launch_bounds__(256, 4)
void transpose_cvt_kernel(const float* __restrict__ we1, unsigned short* __restrict__ we1T,
                          const float* __restrict__ we2, unsigned short* __restrict__ we2T){
  int b = blockIdx.x;
  const float* in; unsigned short* out; int R, C;
  if (b < 1024){ in = we1; out = we1T; R = 512; C = 1024; }
  else         { in = we2; out = we2T; R = 1024; C = 512; b -= 1024; }
  const int tilesR = R >> 6, tilesC = C >> 6;
  const int e = b / (tilesR * tilesC);
  const int rem = b % (tilesR * tilesC);
  const int rb = (rem / tilesC) << 6;
  const int cb = (rem % tilesC) << 6;
  const float* src = in + (size_t)e * R * C;
  unsigned short* dst = out + (size_t)e * R * C;
  __shared__ float t[64][65];
  const int r0 = threadIdx.x >> 4;
  const int c4 = (threadIdx.x & 15) << 2;
  #pragma unroll
  for (int p = 0; p < 4; ++p){
    int r = r0 + (p << 4);
    const float4 v = *(const float4*)(src + (size_t)(rb + r) * C + cb + c4);
    t[r][c4+0] = v.x; t[r][c4+1] = v.y; t[r][c4+2] = v.z; t[r][c4+3] = v.w;
  }
  __syncthreads();
  #pragma unroll
  for (int p = 0; p < 4; ++p){
    int cr = r0 + (p << 4);
    ushort4 o;
    o.x = f2bf(t[c4+0][cr]); o.y = f2bf(t[c4+1][cr]);
    o.z = f2bf(t[c4+2][cr]); o.w = f2bf(t[c4+3][cr]);
    *(ushort4*)(dst + (size_t)(cb + cr) * R + rb + c4) = o;
  }
}

// ---------------------------------------------------------------------------
// Gate GEMM1 (fp32) + fused x->bf16: h = relu(x @ gw1 + gb1); xbf = bf16(x).
// Thread tile 8 tok x 8 col: tg=tid>>5 owns toks tg*8..+7; cgr=tid&31 owns
// cols {4cgr..+3, 128+4cgr..+3}. Per k: 2 conflict-free wv b128 (lanes 0-31
// -> cols 0-127 contiguous) + 2 broadcast xs b128 -> 64 FMA / 4 reads.
// Register prefetch of next slice kept from R14.
// ---------------------------------------------------------------------------
__global__ __launch_bounds__(256)
void gate_gemm1_kernel(const float* __restrict__ x, const float* __restrict__ gw1,
                       const float* __restrict__ gb1, float* __restrict__ h,
                       unsigned short* __restrict__ xbf){
  __shared__ float xs[32][68];          // [k][tok]
  __shared__ float g1s[32][256];        // [k][col]
  const int tid = threadIdx.x;
  const int t0 = blockIdx.x << 6;
  const int tg = tid >> 5;              // token group: toks tg*8..+7
  const int cgr = tid & 31;             // cols 4cgr..+3 and 128+4cgr..+3

  const int xtok = tid >> 2, xk8 = (tid & 3) << 3;   // x stage mapping
  const int pr = tid >> 6, pc = (tid & 63) << 2;     // gw1 prefetch mapping

  float4 ng0, ng1, ng2, ng3, ng4, ng5, ng6, ng7;
  float4 nx0, nx1;
  { // prologue: load slice 0 into regs
    const float* gp = gw1 + (size_t)pr * 256 + pc;
    ng0 = *(const float4*)(gp);
    ng1 = *(const float4*)(gp + 4*256);
    ng2 = *(const float4*)(gp + 8*256);
    ng3 = *(const float4*)(gp + 12*256);
    ng4 = *(const float4*)(gp + 16*256);
    ng5 = *(const float4*)(gp + 20*256);
    ng6 = *(const float4*)(gp + 24*256);
    ng7 = *(const float4*)(gp + 28*256);
    nx0 = *(const float4*)(x + (size_t)(t0 + xtok) * 512 + xk8);
    nx1 = *(const float4*)(x + (size_t)(t0 + xtok) * 512 + xk8 + 4);
  }

  float acc[8][8];
  #pragma unroll
  for (int t = 0; t < 8; ++t)
    #pragma unroll
    for (int c = 0; c < 8; ++c) acc[t][c] = 0.f;

  for (int kb = 0; kb < 512; kb += 32){
    { // write staged slice kb to LDS + emit xbf
      xs[xk8+0][xtok] = nx0.x; xs[xk8+1][xtok] = nx0.y;
      xs[xk8+2][xtok] = nx0.z; xs[xk8+3][xtok] = nx0.w;
      xs[xk8+4][xtok] = nx1.x; xs[xk8+5][xtok] = nx1.y;
      xs[xk8+6][xtok] = nx1.z; xs[xk8+7][xtok] = nx1.w;
      ushort4 o0, o1;
      o0.x = f2bf(nx0.x); o0.y = f2bf(nx0.y); o0.z = f2bf(nx0.z); o0.w = f2bf(nx0.w);
      o1.x = f2bf(nx1.x); o1.y = f2bf(nx1.y); o1.z = f2bf(nx1.z); o1.w = f2bf(nx1.w);
      *(ushort4*)(xbf + (size_t)(t0 + xtok) * 512 + kb + xk8)     = o0;
      *(ushort4*)(xbf + (size_t)(t0 + xtok) * 512 + kb + xk8 + 4) = o1;
      float* gq = &g1s[pr][pc];
      *(float4*)(gq)           = ng0;
      *(float4*)(gq + 4*256)   = ng1;
      *(float4*)(gq + 8*256)   = ng2;
      *(float4*)(gq + 12*256)  = ng3;
      *(float4*)(gq + 16*256)  = ng4;
      *(float4*)(gq + 20*256)  = ng5;
      *(float4*)(gq + 24*256)  = ng6;
      *(float4*)(gq + 28*256)  = ng7;
    }
    __syncthreads();
    if (kb < 480){ // issue next slice's loads; FMA block hides them
      const float* gp = gw1 + (size_t)(kb + 32 + pr) * 256 + pc;
      ng0 = *(const float4*)(gp);
      ng1 = *(const float4*)(gp + 4*256);
      ng2 = *(const float4*)(gp + 8*256);
      ng3 = *(const float4*)(gp + 12*256);
      ng4 = *(const float4*)(gp + 16*256);
      ng5 = *(const float4*)(gp + 20*256);
      ng6 = *(const float4*)(gp + 24*256);
      ng7 = *(const float4*)(gp + 28*256);
      nx0 = *(const float4*)(x + (size_t)(t0 + xtok) * 512 + kb + 32 + xk8);
      nx1 = *(const float4*)(x + (size_t)(t0 + xtok) * 512 + kb + 32 + xk8 + 4);
    }
    #pragma unroll 4
    for (int k = 0; k < 32; ++k){
      const float4 wv0 = *(const float4*)&g1s[k][cgr << 2];
      const float4 wv1 = *(const float4*)&g1s[k][128 + (cgr << 2)];
      const float4 xa = *(const float4*)&xs[k][(tg << 3)];
      const float4 xb = *(const float4*)&xs[k][(tg << 3) + 4];
      #define FMA8(T, XV) \
        acc[T][0] = fmaf(XV, wv0.x, acc[T][0]); acc[T][1] = fmaf(XV, wv0.y, acc[T][1]); \
        acc[T][2] = fmaf(XV, wv0.z, acc[T][2]); acc[T][3] = fmaf(XV, wv0.w, acc[T][3]); \
        acc[T][4] = fmaf(XV, wv1.x, acc[T][4]); acc[T][5] = fmaf(XV, wv1.y, acc[T][5]); \
        acc[T][6] = fmaf(XV, wv1.z, acc[T][6]); acc[T][7] = fmaf(XV, wv1.w, acc[T][7]);
      FMA8(0, xa.x) FMA8(1, xa.y) FMA8(2, xa.z) FMA8(3, xa.w)
      FMA8(4, xb.x) FMA8(5, xb.y) FMA8(6, xb.z) FMA8(7, xb.w)
      #undef FMA8
    }
    __syncthreads();
  }

  const float4 b0 = *(const float4*)(gb1 + (cgr << 2));
  const float4 b1 = *(const float4*)(gb1 + 128 + (cgr << 2));
  #pragma unroll
  for (int t = 0; t < 8; ++t){
    float* hp = h + (size_t)(t0 + (tg << 3) + t) * 256 + (cgr << 2);
    float4 o;
    o.x = fmaxf(acc[t][0] + b0.x, 0.f);
    o.y = fmaxf(acc[t][1] + b0.y, 0.f);
    o.z = fmaxf(acc[t][2] + b0.z, 0.f);
    o.w = fmaxf(acc[t][3] + b0.w, 0.f);
    *(float4*)hp = o;
    o.x = fmaxf(acc[t][4] + b1.x, 0.f);
    o.y = fmaxf(acc[t][5] + b1.y, 0.f);
    o.z = fmaxf(acc[t][6] + b1.z, 0.f);
    o.w = fmaxf(acc[t][7] + b1.w, 0.f);
    *(float4*)(hp + 128) = o;
  }
}

// ---------------------------------------------------------------------------
// Gate2: logits, softmax, top2, re-softmax, block-aggregated scatter.
// Records tpos[token*2 + {0,1}] = (e<<16)|list_pos for the combiner.
// ---------------------------------------------------------------------------
__global__ __launch_bounds__(256, 2)
void gate2_kernel(const float* __restrict__ h, const float* __restrict__ gw2,
                  const float* __restrict__ gb2,
                  int* __restrict__ counts, int* __restrict__ pair_tok,
                  float* __restrict__ pair_w, int* __restrict__ tpos){
  __shared__ float g2s[256 * 9];
  __shared__ int   lcnt[8];
  __shared__ int   lbase[8];
  __shared__ int   lpre[9];
  __shared__ int   ltok[8][256];
  __shared__ float lw[8][256];
  const int tid = threadIdx.x;
  const int t0 = blockIdx.x << 8;

  #pragma unroll
  for (int p = 0; p < 8; ++p){
    int idx = tid + (p << 8);
    g2s[(idx >> 3) * 9 + (idx & 7)] = gw2[idx];
  }
  if (tid < 8) lcnt[tid] = 0;
  __syncthreads();

  const int token = t0 + tid;
  float pl[8];
  #pragma unroll
  for (int e = 0; e < 8; ++e) pl[e] = gb2[e];
  for (int j = 0; j < 64; ++j){
    const float4 hv = *(const float4*)(h + (size_t)token * 256 + (j << 2));
    #pragma unroll
    for (int i = 0; i < 4; ++i){
      const float hx = ((const float*)&hv)[i];
      #pragma unroll
      for (int e = 0; e < 8; ++e)
        pl[e] = fmaf(hx, g2s[((j << 2) + i) * 9 + e], pl[e]);
    }
  }
  float m = pl[0];
  #pragma unroll
  for (int e = 1; e < 8; ++e) m = fmaxf(m, pl[e]);
  float p[8]; float s = 0.f;
  #pragma unroll
  for (int e = 0; e < 8; ++e){ p[e] = expf(pl[e] - m); s += p[e]; }
  float inv = 1.f / s;
  float m1 = -1.f, m2 = -1.f; int i1 = 0, i2 = 0;
  #pragma unroll
  for (int e = 0; e < 8; ++e){
    float pe = p[e] * inv;
    if (pe > m1){ m2 = m1; i2 = i1; m1 = pe; i1 = e; }
    else if (pe > m2){ m2 = pe; i2 = e; }
  }
  float e21 = expf(m2 - m1);
  float w1 = 1.f / (1.f + e21);
  float w2 = 1.f - w1;
  int p1 = atomicAdd(&lcnt[i1], 1); ltok[i1][p1] = token; lw[i1][p1] = w1;
  int p2 = atomicAdd(&lcnt[i2], 1); ltok[i2][p2] = token; lw[i2][p2] = w2;
  __syncthreads();
  if (tid < 8) lbase[tid] = atomicAdd(&counts[tid], lcnt[tid]);
  if (tid == 0){
    lpre[0] = 0;
    #pragma unroll
    for (int e = 0; e < 8; ++e) lpre[e+1] = lpre[e] + lcnt[e];
  }
  __syncthreads();
  tpos[(size_t)token * 2]     = (i1 << 16) + lbase[i1] + p1;
  tpos[(size_t)token * 2 + 1] = (i2 << 16) + lbase[i2] + p2;
  const int total = lpre[8];
  for (int idx = tid; idx < total; idx += 256){
    int e = 0;
    #pragma unroll
    for (int q = 0; q < 7; ++q) e += (idx >= lpre[q + 1]) ? 1 : 0;
    const int i = idx - lpre[e];
    const int dst = (e << 16) + lbase[e] + i;
    pair_tok[dst] = ltok[e][i];
    pair_w[dst]   = lw[e][i];
  }
}

// ---------------------------------------------------------------------------
// Scan: chunk offsets (128-token chunks) + exact token prefix offsets.
// ---------------------------------------------------------------------------
__global__ void scan_kernel(const int* __restrict__ counts, int* __restrict__ offs,
                            int* __restrict__ toffs){
  if (threadIdx.x == 0){
    int o = 0, t = 0;
    #pragma unroll
    for (int e = 0; e < 8; ++e){
      offs[e] = o; o += (counts[e] + 127) >> 7;
      toffs[e] = t; t += counts[e];
    }
    offs[8] = o; toffs[8] = t;
  }
}

// ---------------------------------------------------------------------------
// eg1: h[seq][1024] = gelu(gather(x) @ we1 + be1), bf16.
// 32KB LDS, 4 blocks/CU, XCD-chunked swizzle, swapped MFMA operands,
// tanh-gelu epilogue. (R13-verified)
// ---------------------------------------------------------------------------
__global__ __launch_bounds__(256, 4)
void eg1_kernel(const unsigned short* __restrict__ xbf,
                const unsigned short* __restrict__ we1T,   // [E][1024][512]
                const float* __restrict__ be1,
                const int* __restrict__ counts, const int* __restrict__ offs,
                const int* __restrict__ toffs, const int* __restrict__ pair_tok,
                unsigned short* __restrict__ h){
  const int g = (blockIdx.x & 7) * 1032 + (blockIdx.x >> 3);
  const int chunk = g >> 3, nt = g & 7;
  if (chunk >= offs[8]) return;
  int e = 0;
  #pragma unroll
  for (int q = 0; q < 7; ++q) e += (chunk >= offs[q+1]) ? 1 : 0;
  const int cnt = counts[e];
  const int base = (chunk - offs[e]) << 7;
  const int n0 = nt << 7;
  const int tid = threadIdx.x;
  const int lane = tid & 63;
  const int wv = tid >> 6;
  const int wr = wv >> 1, wc = wv & 1;
  const int lrow = lane & 15, kgrp = lane >> 4;

  __shared__ char lds[32768];
  char* const As = lds;
  char* const Bs = lds + 16384;

  const int srow = tid >> 3;
  const int sdelta = ((tid & 7) << 4) ^ ((srow & 7) << 4);
  unsigned aoff[4];
  #pragma unroll
  for (int i = 0; i < 4; ++i){
    int rr = base + srow + (i << 5);
    int tok = (rr < cnt) ? pair_tok[(e << 16) + rr] : 0;
    aoff[i] = ((unsigned)tok) << 10;
  }
  const char* const xb  = (const char*)xbf;
  const char* const w1b = (const char*)we1T + ((size_t)e << 20);

  f32x4 acc[4][4];                       // [hcol-frag][token-frag]
  #pragma unroll
  for (int i = 0; i < 4; ++i)
    #pragma unroll
    for (int j = 0; j < 4; ++j) acc[i][j] = (f32x4)0.f;

  const int sw = (lrow & 7) << 4;
  for (int kb = 0; kb < 8; ++kb){
    #pragma unroll
    for (int i = 0; i < 4; ++i)
      gload16(xb + aoff[i] + (kb << 7) + sdelta, As + (tid << 4) + (i << 12));
    #pragma unroll
    for (int i = 0; i < 4; ++i)
      gload16(w1b + (size_t)(n0 + srow + (i << 5)) * 1024 + (kb << 7) + sdelta,
              Bs + (tid << 4) + (i << 12));
    __syncthreads();
    #pragma unroll
    for (int s = 0; s < 2; ++s){
      const int kbyte = ((s << 6) + (kgrp << 4)) ^ sw;
      bf16x8 af[4], bf[4];
      #pragma unroll
      for (int f = 0; f < 4; ++f){
        af[f] = *(const bf16x8*)(As + ((wr << 6) + (f << 4) + lrow) * 128 + kbyte);
        bf[f] = *(const bf16x8*)(Bs + ((wc << 6) + (f << 4) + lrow) * 128 + kbyte);
      }
      #pragma unroll
      for (int fb = 0; fb < 4; ++fb)
        #pragma unroll
        for (int fa = 0; fa < 4; ++fa)
          acc[fb][fa] = __builtin_amdgcn_mfma_f32_16x16x32_bf16(bf[fb], af[fa], acc[fb][fa], 0, 0, 0);
    }
    __syncthreads();
  }

  const int hrow0 = toffs[e] + base;
  float4 bias4[4];
  #pragma unroll
  for (int fb = 0; fb < 4; ++fb)
    bias4[fb] = *(const float4*)(be1 + (e << 10) + n0 + (wc << 6) + (fb << 4) + (kgrp << 2));
  #pragma unroll
  for (int fa = 0; fa < 4; ++fa){
    const int tl = (wr << 6) + (fa << 4) + lrow;
    if (base + tl < cnt){
      unsigned short* hp = h + (size_t)(hrow0 + tl) * 1024 + n0 + (wc << 6) + (kgrp << 2);
      #pragma unroll
      for (int fb = 0; fb < 4; ++fb){
        ushort4 o;
        o.x = f2bf(gelu_fast(acc[fb][fa][0] + bias4[fb].x));
        o.y = f2bf(gelu_fast(acc[fb][fa][1] + bias4[fb].y));
        o.z = f2bf(gelu_fast(acc[fb][fa][2] + bias4[fb].z));
        o.w = f2bf(gelu_fast(acc[fb][fa][3] + bias4[fb].w));
        *(ushort4*)(hp + (fb << 4)) = o;
      }
    }
  }
}

// ---------------------------------------------------------------------------
// eg2 (swapped operands): y = h @ we2 + be2 -> ybuf (bf16, no atomics).
// Fallback: atomic accumulate into out. (R13-verified)
// ---------------------------------------------------------------------------
__global__ __launch_bounds__(256, 4)
void eg2_kernel(const unsigned short* __restrict__ h,
                const unsigned short* __restrict__ we2T,   // [E][512][1024]
                const float* __restrict__ be2,
                const int* __restrict__ counts, const int* __restrict__ offs,
                const int* __restrict__ toffs, const int* __restrict__ pair_tok,
                const float* __restrict__ pair_w,
                unsigned short* __restrict__ ybuf,         // may be null
                float* __restrict__ out){
  const int g = (blockIdx.x & 7) * 516 + (blockIdx.x >> 3);
  const int chunk = g >> 2, nt = g & 3;
  if (chunk >= offs[8]) return;
  int e = 0;
  #pragma unroll
  for (int q = 0; q < 7; ++q) e += (chunk >= offs[q+1]) ? 1 : 0;
  const int cnt = counts[e];
  const int base = (chunk - offs[e]) << 7;
  const int n0 = nt << 7;
  const int tid = threadIdx.x;
  const int lane = tid & 63;
  const int wv = tid >> 6;
  const int wr = wv >> 1, wc = wv & 1;
  const int lrow = lane & 15, kgrp = lane >> 4;

  __shared__ char lds[32768];
  char* const As = lds;
  char* const Bs = lds + 16384;

  const int srow = tid >> 3;
  const int sdelta = ((tid & 7) << 4) ^ ((srow & 7) << 4);
  const char* const hb  = (const char*)h + (size_t)(toffs[e] + base) * 2048;
  const char* const w2b = (const char*)we2T + ((size_t)e << 20);

  f32x4 acc[4][4];                       // [outcol-frag][token-frag]
  #pragma unroll
  for (int i = 0; i < 4; ++i)
    #pragma unroll
    for (int j = 0; j < 4; ++j) acc[i][j] = (f32x4)0.f;

  const int sw = (lrow & 7) << 4;
  for (int kb = 0; kb < 16; ++kb){
    #pragma unroll
    for (int i = 0; i < 4; ++i)
      gload16(hb + (size_t)(srow + (i << 5)) * 2048 + (kb << 7) + sdelta,
              As + (tid << 4) + (i << 12));
    #pragma unroll
    for (int i = 0; i < 4; ++i)
      gload16(w2b + (size_t)(n0 + srow + (i << 5)) * 2048 + (kb << 7) + sdelta,
              Bs + (tid << 4) + (i << 12));
    __syncthreads();
    #pragma unroll
    for (int s = 0; s < 2; ++s){
      const int kbyte = ((s << 6) + (kgrp << 4)) ^ sw;
      bf16x8 af[4], bf[4];
      #pragma unroll
      for (int f = 0; f < 4; ++f){
        af[f] = *(const bf16x8*)(As + ((wr << 6) + (f << 4) + lrow) * 128 + kbyte);
        bf[f] = *(const bf16x8*)(Bs + ((wc << 6) + (f << 4) + lrow) * 128 + kbyte);
      }
      #pragma unroll
      for (int fb = 0; fb < 4; ++fb)
        #pragma unroll
        for (int fa = 0; fa < 4; ++fa)
          acc[fb][fa] = __builtin_amdgcn_mfma_f32_16x16x32_bf16(bf[fb], af[fa], acc[fb][fa], 0, 0, 0);
    }
    __syncthreads();
  }

  float4 bias4[4];
  #pragma unroll
  for (int fb = 0; fb < 4; ++fb)
    bias4[fb] = *(const float4*)(be2 + (e << 9) + n0 + (wc << 6) + (fb << 4) + (kgrp << 2));

  if (ybuf){
    const int yrow0 = toffs[e] + base;
    #pragma unroll
    for (int fa = 0; fa < 4; ++fa){
      const int tl = (wr << 6) + (fa << 4) + lrow;
      if (base + tl < cnt){
        unsigned short* yp = ybuf + (size_t)(yrow0 + tl) * 512 + n0 + (wc << 6) + (kgrp << 2);
        #pragma unroll
        for (int fb = 0; fb < 4; ++fb){
          ushort4 o;
          o.x = f2bf(acc[fb][fa][0] + bias4[fb].x);
          o.y = f2bf(acc[fb][fa][1] + bias4[fb].y);
          o.z = f2bf(acc[fb][fa][2] + bias4[fb].z);
          o.w = f2bf(acc[fb][fa][3] + bias4[fb].w);
          *(ushort4*)(yp + (fb << 4)) = o;
        }
      }
    }
  } else {
    #pragma unroll
    for (int fa = 0; fa < 4; ++fa){
      const int tl = (wr << 6) + (fa << 4) + lrow;
      const int r = base + tl;
      if (r < cnt){
        const int tok = pair_tok[(e << 16) + r];
        const float wgt = pair_w[(e << 16) + r];
        float* const orow = out + (size_t)tok * 512 + n0 + (wc << 6) + (kgrp << 2);
        #pragma unroll
        for (int fb = 0; fb < 4; ++fb){
          atomicAdd(orow + (fb << 4) + 0, wgt * (acc[fb][fa][0] + bias4[fb].x));
          atomicAdd(orow + (fb << 4) + 1, wgt * (acc[fb][fa][1] + bias4[fb].y));
          atomicAdd(orow + (fb << 4) + 2, wgt * (acc[fb][fa][2] + bias4[fb].z));
          atomicAdd(orow + (fb << 4) + 3, wgt * (acc[fb][fa][3] + bias4[fb].w));
        }
      }
    }
  }
}

// ---------------------------------------------------------------------------
// Combine: out[t] = w0 * y[seq0] + w1 * y[seq1].
// ---------------------------------------------------------------------------
__global__ __launch_bounds__(256, 8)
void combine_kernel(const unsigned short* __restrict__ ybuf,
                    const int* __restrict__ tpos, const int* __restrict__ toffs,
                    const float* __restrict__ pair_w,
                    float* __restrict__ out){
  const int wg = threadIdx.x >> 6;
  const int lane = threadIdx.x & 63;
  for (int t = (blockIdx.x << 2) + wg; t < 65536; t += 4096 * 4){
    const int d0 = tpos[(size_t)t * 2];
    const int d1 = tpos[(size_t)t * 2 + 1];
    const int seq0 = toffs[d0 >> 16] + (d0 & 0xFFFF);
    const int seq1 = toffs[d1 >> 16] + (d1 & 0xFFFF);
    const float w0 = pair_w[d0];
    const float w1 = pair_w[d1];
    const bf16x8 a = *(const bf16x8*)(ybuf + (size_t)seq0 * 512 + (lane << 3));
    const bf16x8 b = *(const bf16x8*)(ybuf + (size_t)seq1 * 512 + (lane << 3));
    float4 o0, o1;
    o0.x = w0*bf2f((unsigned short)a[0]) + w1*bf2f((unsigned short)b[0]);
    o0.y = w0*bf2f((unsigned short)a[1]) + w1*bf2f((unsigned short)b[1]);
    o0.z = w0*bf2f((unsigned short)a[2]) + w1*bf2f((unsigned short)b[2]);
    o0.w = w0*bf2f((unsigned short)a[3]) + w1*bf2f((unsigned short)b[3]);
    o1.x = w0*bf2f((unsigned short)a[4]) + w1*bf2f((unsigned short)b[4]);
    o1.y = w0*bf2f((unsigned short)a[5]) + w1*bf2f((unsigned short)b[5]);
    o1.z = w0*bf2f((unsigned short)a[6]) + w1*bf2f((unsigned short)b[6]);
    o1.w = w0*bf2f((unsigned short)a[7]) + w1*bf2f((unsigned short)b[7]);
    float* op = out + (size_t)t * 512 + (lane << 3);
    *(float4*)op = o0;
    *(float4*)(op + 4) = o1;
  }
}

// ---------------------------------------------------------------------------
extern "C" void kernel_launch(void* const* d_in, const int* in_sizes, int n_in,
                              void* d_out, int out_size, void* d_ws, size_t ws_size,
                              hipStream_t stream){
  const float* x   = (const float*)d_in[0];
  const float* gw1 = (const float*)d_in[1];
  const float* gb1 = (const float*)d_in[2];
  const float* gw2 = (const float*)d_in[3];
  const float* gb2 = (const float*)d_in[4];
  const float* we1 = (const float*)d_in[5];
  const float* be1 = (const float*)d_in[6];
  const float* we2 = (const float*)d_in[7];
  const float* be2 = (const float*)d_in[8];
  float* out = (float*)d_out;

  char* ws = (char*)d_ws;
  const size_t MiB = 1024 * 1024;
  unsigned short* we1T = (unsigned short*)(ws);                 // 8 MiB
  unsigned short* we2T = (unsigned short*)(ws + 8 * MiB);       // 8 MiB
  int*   pair_tok = (int*)  (ws + 16 * MiB);                    // 2 MiB
  float* pair_w   = (float*)(ws + 18 * MiB);                    // 2 MiB
  int*   counts   = (int*)  (ws + 20 * MiB);                    // 64 B
  int*   offs     = (int*)  (ws + 20 * MiB + 256);              // 64 B
  int*   toffs    = (int*)  (ws + 20 * MiB + 512);              // 64 B
  int*   tpos     = (int*)  (ws + 20 * MiB + 4096);             // 512 KiB
  unsigned short* xbf  = (unsigned short*)(ws + 21 * MiB);      // 64 MiB
  float* ghuf          = (float*)(ws + 85 * MiB);               // 64 MiB (gate h)
  unsigned short* hexp = (unsigned short*)(ws + 85 * MiB);      // 256 MiB, aliases ghuf
  unsigned short* ybuf = (unsigned short*)(ws + 341 * MiB);     // 128 MiB
  const bool have_y = ws_size >= 470 * MiB;

  if (!have_y)
    hipMemsetAsync(d_out, 0, (size_t)out_size * sizeof(float), stream);
  hipMemsetAsync(counts, 0, 256, stream);

  hipLaunchKernelGGL(transpose_cvt_kernel, dim3(2048), dim3(256), 0, stream,
                     we1, we1T, we2, we2T);
  hipLaunchKernelGGL(gate_gemm1_kernel, dim3(1024), dim3(256), 0, stream,
                     x, gw1, gb1, ghuf, xbf);
  hipLaunchKernelGGL(gate2_kernel, dim3(256), dim3(256), 0, stream,
                     ghuf, gw2, gb2, counts, pair_tok, pair_w, tpos);
  hipLaunchKernelGGL(scan_kernel, dim3(1), dim3(64), 0, stream, counts, offs, toffs);

  hipLaunchKernelGGL(eg1_kernel, dim3(8256), dim3(256), 0, stream,
                     xbf, we1T, be1, counts, offs, toffs, pair_tok, hexp);
  hipLaunchKernelGGL(eg2_kernel, dim3(4128), dim3(256), 0, stream,
                     hexp, we2T, be2, counts, offs, toffs, pair_tok, pair_w,
                     have_y ? ybuf : (unsigned short*)nullptr, out);
  if (have_y)
    hipLaunchKernelGGL(combine_kernel, dim3(4096), dim3(256), 0, stream,
                       ybuf, tpos, toffs, pair_w, out);
}